// Round 8
// baseline (169.509 us; speedup 1.0000x reference)
//
#include <hip/hip_runtime.h>
#include <cstdint>

#define B_ 16
#define N_ 2048
#define D_ 256
#define EPS_ 1e-9f

#define AS1 __attribute__((address_space(1)))
#define AS3 __attribute__((address_space(3)))

typedef float f4 __attribute__((ext_vector_type(4)));
typedef __attribute__((ext_vector_type(8))) short short8;

__device__ inline unsigned short f2bf(float x){
  unsigned int u = __float_as_uint(x);
  u = (u + 0x7fffu + ((u >> 16) & 1u)) >> 16;
  return (unsigned short)u;
}
__device__ inline float bf2f(unsigned short u){
  return __uint_as_float(((unsigned int)u) << 16);
}

__device__ float blockReduceSum(float x, float* red){
  int tid = threadIdx.x;
  red[tid] = x; __syncthreads();
  #pragma unroll
  for (int off = 128; off > 0; off >>= 1){
    if (tid < off) red[tid] += red[tid + off];
    __syncthreads();
  }
  float r = red[0]; __syncthreads();
  return r;
}

// fp32 norm + bf16 conversion; grid.y = src select. Also folds all state init.
__global__ __launch_bounds__(256) void prep_kernel(
    const float* __restrict__ preds, const float* __restrict__ labels,
    unsigned short* __restrict__ pabf, unsigned short* __restrict__ pbbf,
    float* __restrict__ pn, float* __restrict__ ln,
    float* __restrict__ cost, float* __restrict__ currency,
    int* __restrict__ dmin, float* __restrict__ PL,
    float* __restrict__ scal, float* __restrict__ out){
  int s = blockIdx.y;
  if (s == 0){
    int i = blockIdx.x * 256 + threadIdx.x;
    if (i < B_ * N_){ cost[i] = 1.f; currency[i] = 1.f; }
    if (i < 2 * B_ * D_) PL[i] = 0.f;
    if (i < B_ * 4) scal[i] = 0.f;
    if (i < B_) dmin[i] = 0x7f7fffff;  // FLT_MAX bits
    if (i == 0) out[0] = 0.f;
  }
  const float* src = s ? labels : preds;
  unsigned short* dst = s ? pbbf : pabf;
  float* norms = s ? ln : pn;
  int gw = (blockIdx.x * blockDim.x + threadIdx.x) >> 6;
  int lane = threadIdx.x & 63;
  const float4 v = ((const float4*)(src + (size_t)gw * D_))[lane];
  float sum = v.x*v.x + v.y*v.y + v.z*v.z + v.w*v.w;
  #pragma unroll
  for (int off = 32; off >= 1; off >>= 1) sum += __shfl_xor(sum, off);
  if (lane == 0) norms[gw] = sum;
  ushort4 o; o.x = f2bf(v.x); o.y = f2bf(v.y); o.z = f2bf(v.z); o.w = f2bf(v.w);
  ((ushort4*)(dst + (size_t)gw * D_))[lane] = o;
}

// d[b][n][m] = pn[n] + ln[m] - 2*dot via bf16 MFMA; NO stores — only per-batch min.
// Round-4 proven geometry (128x128 tile, BK=64, 128-B LDS rows, XOR r&7,
// measured 0 bank conflicts, dbuf, register epilogue). ONLY change vs round 4:
// batch->XCD pinning. Dispatch is round-robin over 8 XCDs (xcd ~= lid&7), so
// b = 2*(lid&7) + (lid>>11) gives each XCD exactly two batches, processed
// sequentially; 16 consecutive same-XCD blocks share tn (B-panel L2-hot).
// Per-XCD working set = one batch's A+B panels = 2 MB <= 4 MB L2.
__global__ __launch_bounds__(256) void gemm_minmax(
    const unsigned short* __restrict__ pa, const unsigned short* __restrict__ pbm,
    const float* __restrict__ pn, const float* __restrict__ ln,
    int* __restrict__ dmin)
{
  int lid = blockIdx.x + 16 * blockIdx.y + 256 * blockIdx.z;
  int b = 2 * (lid & 7) + (lid >> 11);
  int t = (lid >> 3) & 255;
  int tm = (t & 15) * 128, tn = (t >> 4) * 128;
  const unsigned short* A  = pa  + (size_t)b * N_ * D_;
  const unsigned short* Bm = pbm + (size_t)b * N_ * D_;
  __shared__ __align__(16) unsigned short As[2][128 * 64];
  __shared__ __align__(16) unsigned short Bs[2][128 * 64];
  __shared__ float minred[4];
  int tid = threadIdx.x, lane = tid & 63, w = tid >> 6;
  int wm = (w >> 1) * 64, wn = (w & 1) * 64;
  int quad = lane >> 4, l15 = lane & 15;

  // ---- preload epilogue operands (K-independent) into registers ----
  float4 pnr[4];
  float lnr[4];
  #pragma unroll
  for (int i = 0; i < 4; i++)
    pnr[i] = *(const float4*)&pn[(size_t)b * N_ + tm + wm + i * 16 + quad * 4];
  #pragma unroll
  for (int jj = 0; jj < 4; jj++)
    lnr[jj] = ln[(size_t)b * N_ + tn + wn + jj * 16 + l15];

  f4 acc[4][4];
  #pragma unroll
  for (int i = 0; i < 4; i++)
    #pragma unroll
    for (int j = 0; j < 4; j++) acc[i][j] = (f4)0.f;

  int lr = lane >> 3, ch = lane & 7;
  int gch = (ch ^ lr) * 8;           // XOR swizzle on the GLOBAL side (r&7 == lr)

  // prefetch tile 0 into buffer 0
  #pragma unroll
  for (int p = 0; p < 4; p++){
    int R = p * 32 + w * 8;
    int r = R + lr;
    __builtin_amdgcn_global_load_lds(
        (const AS1 unsigned int*)(const void*)&A[(size_t)(tm + r) * D_ + gch],
        (AS3 unsigned int*)(void*)&As[0][R * 64], 16, 0, 0);
    __builtin_amdgcn_global_load_lds(
        (const AS1 unsigned int*)(const void*)&Bm[(size_t)(tn + r) * D_ + gch],
        (AS3 unsigned int*)(void*)&Bs[0][R * 64], 16, 0, 0);
  }

  int buf = 0;
  for (int ki = 0; ki < 4; ki++){
    __syncthreads();   // drains buf's loads (issued one compute-phase ago)
    if (ki < 3){
      int kt = (ki + 1) * 64;
      #pragma unroll
      for (int p = 0; p < 4; p++){
        int R = p * 32 + w * 8;
        int r = R + lr;
        __builtin_amdgcn_global_load_lds(
            (const AS1 unsigned int*)(const void*)&A[(size_t)(tm + r) * D_ + kt + gch],
            (AS3 unsigned int*)(void*)&As[buf ^ 1][R * 64], 16, 0, 0);
        __builtin_amdgcn_global_load_lds(
            (const AS1 unsigned int*)(const void*)&Bm[(size_t)(tn + r) * D_ + kt + gch],
            (AS3 unsigned int*)(void*)&Bs[buf ^ 1][R * 64], 16, 0, 0);
      }
    }
    #pragma unroll
    for (int ks = 0; ks < 2; ks++){
      short8 af[4], bf[4];
      int j = ks * 4 + quad;
      #pragma unroll
      for (int i = 0; i < 4; i++){
        int ra = wm + i * 16 + l15;
        af[i] = *(const short8*)(&As[buf][ra * 64 + ((j ^ (ra & 7)) * 8)]);
        int rb = wn + i * 16 + l15;
        bf[i] = *(const short8*)(&Bs[buf][rb * 64 + ((j ^ (rb & 7)) * 8)]);
      }
      #pragma unroll
      for (int i = 0; i < 4; i++)
        #pragma unroll
        for (int jj = 0; jj < 4; jj++)
          acc[i][jj] = __builtin_amdgcn_mfma_f32_16x16x32_bf16(af[i], bf[jj], acc[i][jj], 0, 0, 0);
    }
    buf ^= 1;
  }

  // epilogue: C/D layout col = lane&15, row = quad*4 + reg — registers only
  float mind = 3.4e38f;
  #pragma unroll
  for (int i = 0; i < 4; i++){
    float pv[4] = {pnr[i].x, pnr[i].y, pnr[i].z, pnr[i].w};
    #pragma unroll
    for (int jj = 0; jj < 4; jj++){
      #pragma unroll
      for (int reg = 0; reg < 4; reg++){
        float v = pv[reg] + lnr[jj] - 2.f * acc[i][jj][reg];
        mind = fminf(mind, v);
      }
    }
  }
  #pragma unroll
  for (int off = 32; off >= 1; off >>= 1) mind = fminf(mind, __shfl_xor(mind, off));
  if (lane == 0) minred[w] = mind;
  __syncthreads();
  if (tid == 0){
    float m = fminf(fminf(minred[0], minred[1]), fminf(minred[2], minred[3]));
    atomicMin(&dmin[b], __float_as_int(fmaxf(m, 0.f)));
  }
}

// Exact fallback for the 6 negative exp-factors (skipped when provably
// negligible: B*N^2*dmax*e^{ef*dmin}/EPS < 1e-3 iff ef*(dmin-8) < -55),
// followed by the ef=0 closed-form scalars.
__global__ __launch_bounds__(256) void fb_all(
    const unsigned short* __restrict__ pabf, const unsigned short* __restrict__ pbbf,
    const float* __restrict__ pn, const float* __restrict__ ln,
    float* __restrict__ cost, float* __restrict__ currency,
    const int* __restrict__ dmin, float* __restrict__ out,
    float* __restrict__ alpha, float* __restrict__ v, float* __restrict__ scal)
{
  const float EF[6] = {-256.f, -64.f, -16.f, -4.f, -1.f, -0.25f};
  int b = blockIdx.x, tid = threadIdx.x;
  float dm = __int_as_float(dmin[b]);
  __shared__ float red[256];
  __shared__ float alpha_l[N_];
  __shared__ float prow[D_];
  const unsigned short* A  = pabf + (size_t)b * N_ * D_;
  const unsigned short* Bm = pbbf + (size_t)b * N_ * D_;
  const float* pnb = pn + (size_t)b * N_;
  const float* lnb = ln + (size_t)b * N_;
  float* costb = cost + (size_t)b * N_;
  float* curb  = currency + (size_t)b * N_;
  for (int it = 0; it < 6; it++){
    float ef = EF[it];
    if (ef * (dm - 8.f) < -55.f) continue;   // provably negligible contribution
    // ---- exact slow path (not expected to execute for this input) ----
    float cost_c[8], colsum_c[8], bw_c[8], costnew_c[8];
    #pragma unroll
    for (int j = 0; j < 8; j++){ cost_c[j] = costb[j*256+tid]; colsum_c[j] = 0.f; }
    for (int r = 0; r < N_; r++){
      prow[tid] = bf2f(A[(size_t)r * D_ + tid]);
      __syncthreads();
      float s_c[8], rs = 0.f;
      for (int j = 0; j < 8; j++){
        int m = j*256+tid; float dot = 0.f;
        for (int k = 0; k < D_; k++) dot += prow[k] * bf2f(Bm[(size_t)m * D_ + k]);
        float d = pnb[r] + lnb[m] - 2.f*dot;
        float s = __expf(ef * d) * cost_c[j];
        s_c[j] = s; rs += s;
      }
      float tot = blockReduceSum(rs, red);
      float a = curb[r] / (tot + EPS_);
      if (tid == 0) alpha_l[r] = a;
      #pragma unroll
      for (int j = 0; j < 8; j++) colsum_c[j] += s_c[j] * a;
      __syncthreads();
    }
    #pragma unroll
    for (int j = 0; j < 8; j++){
      float cs = colsum_c[j];
      float bw = fminf(cost_c[j] / (cs + EPS_), 1.f);
      bw_c[j] = bw; costnew_c[j] = fmaxf(cost_c[j] - bw*cs, 0.f);
    }
    float contrib = 0.f;
    for (int r = 0; r < N_; r++){
      prow[tid] = bf2f(A[(size_t)r * D_ + tid]);
      __syncthreads();
      float a = alpha_l[r], rbs = 0.f;
      for (int j = 0; j < 8; j++){
        int m = j*256+tid; float dot = 0.f;
        for (int k = 0; k < D_; k++) dot += prow[k] * bf2f(Bm[(size_t)m * D_ + k]);
        float d = pnb[r] + lnb[m] - 2.f*dot;
        float bid = __expf(ef * d) * cost_c[j] * a * bw_c[j];
        rbs += bid; contrib += bid * d;
      }
      float tot = blockReduceSum(rbs, red);
      if (tid == 0) curb[r] = fmaxf(curb[r] - tot, 0.f);
      __syncthreads();
    }
    #pragma unroll
    for (int j = 0; j < 8; j++) costb[j*256+tid] = costnew_c[j];
    float ctot = blockReduceSum(contrib, red);
    if (tid == 0) atomicAdd(out, ctot);
    __syncthreads();
  }
  // ---- fused ef=0 closed-form scalars: exp(0*d)=1 exactly, so
  // sum(bids*d) = Spn*Sv + Sa*Sln - 2*(sum alpha*p).(sum v*l). ----
  float* ab = alpha + (size_t)b * N_;
  float* vb = v + (size_t)b * N_;
  float s = 0.f;
  #pragma unroll
  for (int j = 0; j < 8; j++) s += costb[j*256+tid];
  float Sc = blockReduceSum(s, red);
  float sa = 0.f, spn = 0.f;
  #pragma unroll
  for (int j = 0; j < 8; j++){
    int i = j*256+tid;
    float a = curb[i] / (Sc + EPS_);
    ab[i] = a; sa += a; spn += a * pnb[i];
  }
  float Sa  = blockReduceSum(sa, red);
  float Spn = blockReduceSum(spn, red);
  float sv = 0.f, sln = 0.f;
  #pragma unroll
  for (int j = 0; j < 8; j++){
    int i = j*256+tid;
    float c = costb[j*256+tid];
    float bw = fminf(c / (c * Sa + EPS_), 1.f);
    float vv = c * bw;
    vb[i] = vv; sv += vv; sln += vv * lnb[i];
  }
  float Sv  = blockReduceSum(sv, red);
  float Sln = blockReduceSum(sln, red);
  if (tid == 0){
    scal[b*4+0] = Sa; scal[b*4+1] = Sv; scal[b*4+2] = Spn; scal[b*4+3] = Sln;
  }
}

// P_b = sum_r alpha_r * preds[b][r][:], L_b = sum_m v_m * labels[b][m][:]
__global__ __launch_bounds__(256) void cf_wsum(
    const unsigned short* __restrict__ pabf, const unsigned short* __restrict__ pbbf,
    const float* __restrict__ alpha, const float* __restrict__ v,
    float* __restrict__ PL)
{
  int chunk = blockIdx.x, src = blockIdx.y, b = blockIdx.z, tid = threadIdx.x;
  int g = tid >> 6, c4 = (tid & 63) * 4;
  const unsigned short* X = (src ? pbbf : pabf) + ((size_t)b * N_ + chunk * 64) * D_;
  const float* wv = (src ? v : alpha) + (size_t)b * N_ + chunk * 64;
  __shared__ float wl[64];
  __shared__ float part[4][D_];
  if (tid < 64) wl[tid] = wv[tid];
  __syncthreads();
  f4 acc = (f4)0.f;
  for (int r = g * 16; r < g * 16 + 16; r++){
    uint2 pk = *(const uint2*)&X[(size_t)r * D_ + c4];
    float wr = wl[r];
    acc[0] = fmaf(wr, __uint_as_float(pk.x << 16), acc[0]);
    acc[1] = fmaf(wr, __uint_as_float(pk.x & 0xffff0000u), acc[1]);
    acc[2] = fmaf(wr, __uint_as_float(pk.y << 16), acc[2]);
    acc[3] = fmaf(wr, __uint_as_float(pk.y & 0xffff0000u), acc[3]);
  }
  #pragma unroll
  for (int q = 0; q < 4; q++) part[g][c4 + q] = acc[q];
  __syncthreads();
  float s = part[0][tid] + part[1][tid] + part[2][tid] + part[3][tid];
  atomicAdd(&PL[((size_t)src * B_ + b) * D_ + tid], s);
}

__global__ __launch_bounds__(256) void cf_final(
    const float* __restrict__ PL, const float* __restrict__ scal,
    float* __restrict__ out)
{
  int b = blockIdx.x, tid = threadIdx.x;
  __shared__ float red[256];
  float p = PL[(size_t)b * D_ + tid] * PL[((size_t)B_ + b) * D_ + tid];
  float dot = blockReduceSum(p, red);
  if (tid == 0){
    float Sa = scal[b*4+0], Sv = scal[b*4+1], Spn = scal[b*4+2], Sln = scal[b*4+3];
    atomicAdd(out, Spn * Sv + Sa * Sln - 2.f * dot);
  }
}

extern "C" void kernel_launch(void* const* d_in, const int* in_sizes, int n_in,
                              void* d_out, int out_size, void* d_ws, size_t ws_size,
                              hipStream_t stream)
{
  const float* preds  = (const float*)d_in[0];
  const float* labels = (const float*)d_in[1];
  float* out = (float*)d_out;
  char* ws = (char*)d_ws;
  const size_t BN = (size_t)B_ * N_;
  size_t off = 0;
  float* cost     = (float*)(ws + off); off += BN * 4;
  float* currency = (float*)(ws + off); off += BN * 4;
  float* alpha    = (float*)(ws + off); off += BN * 4;
  float* v        = (float*)(ws + off); off += BN * 4;
  float* pn       = (float*)(ws + off); off += BN * 4;
  float* ln       = (float*)(ws + off); off += BN * 4;
  int*   dmin     = (int*)(ws + off);   off += 256;
  float* scal     = (float*)(ws + off); off += 256;
  float* PL       = (float*)(ws + off); off += (size_t)2 * B_ * D_ * 4;
  unsigned short* pabf = (unsigned short*)(ws + off); off += BN * D_ * 2;
  unsigned short* pbbf = (unsigned short*)(ws + off); off += BN * D_ * 2;

  prep_kernel<<<dim3((unsigned)(BN / 4), 2), 256, 0, stream>>>(
      preds, labels, pabf, pbbf, pn, ln, cost, currency, dmin, PL, scal, out);
  gemm_minmax<<<dim3(16, 16, B_), 256, 0, stream>>>(pabf, pbbf, pn, ln, dmin);
  fb_all<<<dim3(B_), 256, 0, stream>>>(pabf, pbbf, pn, ln, cost, currency, dmin, out,
                                       alpha, v, scal);
  cf_wsum<<<dim3(32, 2, B_), 256, 0, stream>>>(pabf, pbbf, alpha, v, PL);
  cf_final<<<dim3(B_), 256, 0, stream>>>(PL, scal, out);
}

// Round 9
// 158.972 us; speedup vs baseline: 1.0663x; 1.0663x over previous
//
#include <hip/hip_runtime.h>
#include <cstdint>

#define B_ 16
#define N_ 2048
#define D_ 256
#define EPS_ 1e-9f

#define AS1 __attribute__((address_space(1)))
#define AS3 __attribute__((address_space(3)))

typedef float f4 __attribute__((ext_vector_type(4)));
typedef __attribute__((ext_vector_type(8))) short short8;

__device__ inline unsigned short f2bf(float x){
  unsigned int u = __float_as_uint(x);
  u = (u + 0x7fffu + ((u >> 16) & 1u)) >> 16;
  return (unsigned short)u;
}
__device__ inline float bf2f(unsigned short u){
  return __uint_as_float(((unsigned int)u) << 16);
}

__device__ float blockReduceSum(float x, float* red){
  int tid = threadIdx.x;
  red[tid] = x; __syncthreads();
  #pragma unroll
  for (int off = 128; off > 0; off >>= 1){
    if (tid < off) red[tid] += red[tid + off];
    __syncthreads();
  }
  float r = red[0]; __syncthreads();
  return r;
}

// fp32 norm + bf16 conversion; grid.y = src select. Also folds all state init.
__global__ __launch_bounds__(256) void prep_kernel(
    const float* __restrict__ preds, const float* __restrict__ labels,
    unsigned short* __restrict__ pabf, unsigned short* __restrict__ pbbf,
    float* __restrict__ pn, float* __restrict__ ln,
    float* __restrict__ cost, float* __restrict__ currency,
    int* __restrict__ dmin, float* __restrict__ PL,
    float* __restrict__ scal, float* __restrict__ out){
  int s = blockIdx.y;
  if (s == 0){
    int i = blockIdx.x * 256 + threadIdx.x;
    if (i < B_ * N_){ cost[i] = 1.f; currency[i] = 1.f; }
    if (i < 2 * B_ * D_) PL[i] = 0.f;
    if (i < B_ * 4) scal[i] = 0.f;
    if (i < B_) dmin[i] = 0x7f7fffff;  // FLT_MAX bits
    if (i == 0) out[0] = 0.f;
  }
  const float* src = s ? labels : preds;
  unsigned short* dst = s ? pbbf : pabf;
  float* norms = s ? ln : pn;
  int gw = (blockIdx.x * blockDim.x + threadIdx.x) >> 6;
  int lane = threadIdx.x & 63;
  const float4 v = ((const float4*)(src + (size_t)gw * D_))[lane];
  float sum = v.x*v.x + v.y*v.y + v.z*v.z + v.w*v.w;
  #pragma unroll
  for (int off = 32; off >= 1; off >>= 1) sum += __shfl_xor(sum, off);
  if (lane == 0) norms[gw] = sum;
  ushort4 o; o.x = f2bf(v.x); o.y = f2bf(v.y); o.z = f2bf(v.z); o.w = f2bf(v.w);
  ((ushort4*)(dst + (size_t)gw * D_))[lane] = o;
}

// d[b][n][m] = pn[n] + ln[m] - 2*dot via bf16 MFMA; NO stores — only per-batch min.
// 256x256 block tile (4x the C-area per byte staged: L2 traffic 1.07 GB -> 268 MB),
// 512 threads, wave tile 128x64, BK=64, dbuf LDS = 128 KB (1 block/CU).
// Proven-conflict-free LDS layout (128-B rows, XOR r&7) + measured-ideal
// batch->XCD pinning (FETCH = 16.5 MB = input size exactly, round 8).
__global__ __launch_bounds__(512, 2) void gemm_minmax(
    const unsigned short* __restrict__ pa, const unsigned short* __restrict__ pbm,
    const float* __restrict__ pn, const float* __restrict__ ln,
    int* __restrict__ dmin)
{
  int lid = blockIdx.x;              // 1024 blocks, round-robin over 8 XCDs
  int l = lid >> 3;                  // 0..127 sequential per XCD
  int b = 2 * (lid & 7) + (l >> 6);  // 2 batches per XCD
  int t = l & 63;
  int tm = (t & 7) * 256, tn = (t >> 3) * 256;  // tm fastest: B-slice stays L2-hot
  const unsigned short* A  = pa  + (size_t)b * N_ * D_;
  const unsigned short* Bm = pbm + (size_t)b * N_ * D_;
  __shared__ __align__(16) unsigned short As[2][256 * 64];
  __shared__ __align__(16) unsigned short Bs[2][256 * 64];
  __shared__ float minred[8];
  int tid = threadIdx.x, lane = tid & 63, w = tid >> 6;
  int wm = (w >> 2) * 128, wn = (w & 3) * 64;
  int quad = lane >> 4, l15 = lane & 15;

  // ---- preload epilogue operands (K-independent) into registers ----
  float4 pnr[8];
  float lnr[4];
  #pragma unroll
  for (int i = 0; i < 8; i++)
    pnr[i] = *(const float4*)&pn[(size_t)b * N_ + tm + wm + i * 16 + quad * 4];
  #pragma unroll
  for (int jj = 0; jj < 4; jj++)
    lnr[jj] = ln[(size_t)b * N_ + tn + wn + jj * 16 + l15];

  f4 acc[8][4];
  #pragma unroll
  for (int i = 0; i < 8; i++)
    #pragma unroll
    for (int j = 0; j < 4; j++) acc[i][j] = (f4)0.f;

  int lr = lane >> 3, ch = lane & 7;
  int gch = (ch ^ lr) * 8;           // XOR swizzle on the GLOBAL side (r&7 == lr)

  // prefetch tile 0 into buffer 0 (4 rounds of 64 rows each for As and Bs)
  #pragma unroll
  for (int p = 0; p < 4; p++){
    int R = p * 64 + w * 8;
    int r = R + lr;
    __builtin_amdgcn_global_load_lds(
        (const AS1 unsigned int*)(const void*)&A[(size_t)(tm + r) * D_ + gch],
        (AS3 unsigned int*)(void*)&As[0][R * 64], 16, 0, 0);
    __builtin_amdgcn_global_load_lds(
        (const AS1 unsigned int*)(const void*)&Bm[(size_t)(tn + r) * D_ + gch],
        (AS3 unsigned int*)(void*)&Bs[0][R * 64], 16, 0, 0);
  }

  int buf = 0;
  for (int ki = 0; ki < 4; ki++){
    __syncthreads();   // drains buf's loads (issued one compute-phase ago)
    if (ki < 3){
      int kt = (ki + 1) * 64;
      #pragma unroll
      for (int p = 0; p < 4; p++){
        int R = p * 64 + w * 8;
        int r = R + lr;
        __builtin_amdgcn_global_load_lds(
            (const AS1 unsigned int*)(const void*)&A[(size_t)(tm + r) * D_ + kt + gch],
            (AS3 unsigned int*)(void*)&As[buf ^ 1][R * 64], 16, 0, 0);
        __builtin_amdgcn_global_load_lds(
            (const AS1 unsigned int*)(const void*)&Bm[(size_t)(tn + r) * D_ + kt + gch],
            (AS3 unsigned int*)(void*)&Bs[buf ^ 1][R * 64], 16, 0, 0);
      }
    }
    #pragma unroll
    for (int ks = 0; ks < 2; ks++){
      short8 af[8], bf[4];
      int j = ks * 4 + quad;
      #pragma unroll
      for (int i = 0; i < 8; i++){
        int ra = wm + i * 16 + l15;
        af[i] = *(const short8*)(&As[buf][ra * 64 + ((j ^ (ra & 7)) * 8)]);
      }
      #pragma unroll
      for (int jj = 0; jj < 4; jj++){
        int rb = wn + jj * 16 + l15;
        bf[jj] = *(const short8*)(&Bs[buf][rb * 64 + ((j ^ (rb & 7)) * 8)]);
      }
      #pragma unroll
      for (int i = 0; i < 8; i++)
        #pragma unroll
        for (int jj = 0; jj < 4; jj++)
          acc[i][jj] = __builtin_amdgcn_mfma_f32_16x16x32_bf16(af[i], bf[jj], acc[i][jj], 0, 0, 0);
    }
    buf ^= 1;
  }

  // epilogue: C/D layout col = lane&15, row = quad*4 + reg — registers only
  float mind = 3.4e38f;
  #pragma unroll
  for (int i = 0; i < 8; i++){
    float pv[4] = {pnr[i].x, pnr[i].y, pnr[i].z, pnr[i].w};
    #pragma unroll
    for (int jj = 0; jj < 4; jj++){
      #pragma unroll
      for (int reg = 0; reg < 4; reg++){
        float v = pv[reg] + lnr[jj] - 2.f * acc[i][jj][reg];
        mind = fminf(mind, v);
      }
    }
  }
  #pragma unroll
  for (int off = 32; off >= 1; off >>= 1) mind = fminf(mind, __shfl_xor(mind, off));
  if (lane == 0) minred[w] = mind;
  __syncthreads();
  if (tid == 0){
    float m = minred[0];
    #pragma unroll
    for (int q = 1; q < 8; q++) m = fminf(m, minred[q]);
    atomicMin(&dmin[b], __float_as_int(fmaxf(m, 0.f)));
  }
}

// Exact fallback for the 6 negative exp-factors (skipped when provably
// negligible: B*N^2*dmax*e^{ef*dmin}/EPS < 1e-3 iff ef*(dmin-8) < -55),
// followed by the ef=0 closed-form scalars.
__global__ __launch_bounds__(256) void fb_all(
    const unsigned short* __restrict__ pabf, const unsigned short* __restrict__ pbbf,
    const float* __restrict__ pn, const float* __restrict__ ln,
    float* __restrict__ cost, float* __restrict__ currency,
    const int* __restrict__ dmin, float* __restrict__ out,
    float* __restrict__ alpha, float* __restrict__ v, float* __restrict__ scal)
{
  const float EF[6] = {-256.f, -64.f, -16.f, -4.f, -1.f, -0.25f};
  int b = blockIdx.x, tid = threadIdx.x;
  float dm = __int_as_float(dmin[b]);
  __shared__ float red[256];
  __shared__ float alpha_l[N_];
  __shared__ float prow[D_];
  const unsigned short* A  = pabf + (size_t)b * N_ * D_;
  const unsigned short* Bm = pbbf + (size_t)b * N_ * D_;
  const float* pnb = pn + (size_t)b * N_;
  const float* lnb = ln + (size_t)b * N_;
  float* costb = cost + (size_t)b * N_;
  float* curb  = currency + (size_t)b * N_;
  for (int it = 0; it < 6; it++){
    float ef = EF[it];
    if (ef * (dm - 8.f) < -55.f) continue;   // provably negligible contribution
    // ---- exact slow path (not expected to execute for this input) ----
    float cost_c[8], colsum_c[8], bw_c[8], costnew_c[8];
    #pragma unroll
    for (int j = 0; j < 8; j++){ cost_c[j] = costb[j*256+tid]; colsum_c[j] = 0.f; }
    for (int r = 0; r < N_; r++){
      prow[tid] = bf2f(A[(size_t)r * D_ + tid]);
      __syncthreads();
      float s_c[8], rs = 0.f;
      for (int j = 0; j < 8; j++){
        int m = j*256+tid; float dot = 0.f;
        for (int k = 0; k < D_; k++) dot += prow[k] * bf2f(Bm[(size_t)m * D_ + k]);
        float d = pnb[r] + lnb[m] - 2.f*dot;
        float s = __expf(ef * d) * cost_c[j];
        s_c[j] = s; rs += s;
      }
      float tot = blockReduceSum(rs, red);
      float a = curb[r] / (tot + EPS_);
      if (tid == 0) alpha_l[r] = a;
      #pragma unroll
      for (int j = 0; j < 8; j++) colsum_c[j] += s_c[j] * a;
      __syncthreads();
    }
    #pragma unroll
    for (int j = 0; j < 8; j++){
      float cs = colsum_c[j];
      float bw = fminf(cost_c[j] / (cs + EPS_), 1.f);
      bw_c[j] = bw; costnew_c[j] = fmaxf(cost_c[j] - bw*cs, 0.f);
    }
    float contrib = 0.f;
    for (int r = 0; r < N_; r++){
      prow[tid] = bf2f(A[(size_t)r * D_ + tid]);
      __syncthreads();
      float a = alpha_l[r], rbs = 0.f;
      for (int j = 0; j < 8; j++){
        int m = j*256+tid; float dot = 0.f;
        for (int k = 0; k < D_; k++) dot += prow[k] * bf2f(Bm[(size_t)m * D_ + k]);
        float d = pnb[r] + lnb[m] - 2.f*dot;
        float bid = __expf(ef * d) * cost_c[j] * a * bw_c[j];
        rbs += bid; contrib += bid * d;
      }
      float tot = blockReduceSum(rbs, red);
      if (tid == 0) curb[r] = fmaxf(curb[r] - tot, 0.f);
      __syncthreads();
    }
    #pragma unroll
    for (int j = 0; j < 8; j++) costb[j*256+tid] = costnew_c[j];
    float ctot = blockReduceSum(contrib, red);
    if (tid == 0) atomicAdd(out, ctot);
    __syncthreads();
  }
  // ---- fused ef=0 closed-form scalars: exp(0*d)=1 exactly, so
  // sum(bids*d) = Spn*Sv + Sa*Sln - 2*(sum alpha*p).(sum v*l). ----
  float* ab = alpha + (size_t)b * N_;
  float* vb = v + (size_t)b * N_;
  float s = 0.f;
  #pragma unroll
  for (int j = 0; j < 8; j++) s += costb[j*256+tid];
  float Sc = blockReduceSum(s, red);
  float sa = 0.f, spn = 0.f;
  #pragma unroll
  for (int j = 0; j < 8; j++){
    int i = j*256+tid;
    float a = curb[i] / (Sc + EPS_);
    ab[i] = a; sa += a; spn += a * pnb[i];
  }
  float Sa  = blockReduceSum(sa, red);
  float Spn = blockReduceSum(spn, red);
  float sv = 0.f, sln = 0.f;
  #pragma unroll
  for (int j = 0; j < 8; j++){
    int i = j*256+tid;
    float c = costb[j*256+tid];
    float bw = fminf(c / (c * Sa + EPS_), 1.f);
    float vv = c * bw;
    vb[i] = vv; sv += vv; sln += vv * lnb[i];
  }
  float Sv  = blockReduceSum(sv, red);
  float Sln = blockReduceSum(sln, red);
  if (tid == 0){
    scal[b*4+0] = Sa; scal[b*4+1] = Sv; scal[b*4+2] = Spn; scal[b*4+3] = Sln;
  }
}

// P_b = sum_r alpha_r * preds[b][r][:], L_b = sum_m v_m * labels[b][m][:]
__global__ __launch_bounds__(256) void cf_wsum(
    const unsigned short* __restrict__ pabf, const unsigned short* __restrict__ pbbf,
    const float* __restrict__ alpha, const float* __restrict__ v,
    float* __restrict__ PL)
{
  int chunk = blockIdx.x, src = blockIdx.y, b = blockIdx.z, tid = threadIdx.x;
  int g = tid >> 6, c4 = (tid & 63) * 4;
  const unsigned short* X = (src ? pbbf : pabf) + ((size_t)b * N_ + chunk * 64) * D_;
  const float* wv = (src ? v : alpha) + (size_t)b * N_ + chunk * 64;
  __shared__ float wl[64];
  __shared__ float part[4][D_];
  if (tid < 64) wl[tid] = wv[tid];
  __syncthreads();
  f4 acc = (f4)0.f;
  for (int r = g * 16; r < g * 16 + 16; r++){
    uint2 pk = *(const uint2*)&X[(size_t)r * D_ + c4];
    float wr = wl[r];
    acc[0] = fmaf(wr, __uint_as_float(pk.x << 16), acc[0]);
    acc[1] = fmaf(wr, __uint_as_float(pk.x & 0xffff0000u), acc[1]);
    acc[2] = fmaf(wr, __uint_as_float(pk.y << 16), acc[2]);
    acc[3] = fmaf(wr, __uint_as_float(pk.y & 0xffff0000u), acc[3]);
  }
  #pragma unroll
  for (int q = 0; q < 4; q++) part[g][c4 + q] = acc[q];
  __syncthreads();
  float s = part[0][tid] + part[1][tid] + part[2][tid] + part[3][tid];
  atomicAdd(&PL[((size_t)src * B_ + b) * D_ + tid], s);
}

__global__ __launch_bounds__(256) void cf_final(
    const float* __restrict__ PL, const float* __restrict__ scal,
    float* __restrict__ out)
{
  int b = blockIdx.x, tid = threadIdx.x;
  __shared__ float red[256];
  float p = PL[(size_t)b * D_ + tid] * PL[((size_t)B_ + b) * D_ + tid];
  float dot = blockReduceSum(p, red);
  if (tid == 0){
    float Sa = scal[b*4+0], Sv = scal[b*4+1], Spn = scal[b*4+2], Sln = scal[b*4+3];
    atomicAdd(out, Spn * Sv + Sa * Sln - 2.f * dot);
  }
}

extern "C" void kernel_launch(void* const* d_in, const int* in_sizes, int n_in,
                              void* d_out, int out_size, void* d_ws, size_t ws_size,
                              hipStream_t stream)
{
  const float* preds  = (const float*)d_in[0];
  const float* labels = (const float*)d_in[1];
  float* out = (float*)d_out;
  char* ws = (char*)d_ws;
  const size_t BN = (size_t)B_ * N_;
  size_t off = 0;
  float* cost     = (float*)(ws + off); off += BN * 4;
  float* currency = (float*)(ws + off); off += BN * 4;
  float* alpha    = (float*)(ws + off); off += BN * 4;
  float* v        = (float*)(ws + off); off += BN * 4;
  float* pn       = (float*)(ws + off); off += BN * 4;
  float* ln       = (float*)(ws + off); off += BN * 4;
  int*   dmin     = (int*)(ws + off);   off += 256;
  float* scal     = (float*)(ws + off); off += 256;
  float* PL       = (float*)(ws + off); off += (size_t)2 * B_ * D_ * 4;
  unsigned short* pabf = (unsigned short*)(ws + off); off += BN * D_ * 2;
  unsigned short* pbbf = (unsigned short*)(ws + off); off += BN * D_ * 2;

  prep_kernel<<<dim3((unsigned)(BN / 4), 2), 256, 0, stream>>>(
      preds, labels, pabf, pbbf, pn, ln, cost, currency, dmin, PL, scal, out);
  gemm_minmax<<<dim3(1024), 512, 0, stream>>>(pabf, pbbf, pn, ln, dmin);
  fb_all<<<dim3(B_), 256, 0, stream>>>(pabf, pbbf, pn, ln, cost, currency, dmin, out,
                                       alpha, v, scal);
  cf_wsum<<<dim3(32, 2, B_), 256, 0, stream>>>(pabf, pbbf, alpha, v, PL);
  cf_final<<<dim3(B_), 256, 0, stream>>>(PL, scal, out);
}

// Round 10
// 150.348 us; speedup vs baseline: 1.1274x; 1.0574x over previous
//
#include <hip/hip_runtime.h>
#include <cstdint>

#define B_ 16
#define N_ 2048
#define D_ 256
#define EPS_ 1e-9f

#define AS1 __attribute__((address_space(1)))
#define AS3 __attribute__((address_space(3)))

typedef float f4 __attribute__((ext_vector_type(4)));
typedef __attribute__((ext_vector_type(8))) short short8;

__device__ inline unsigned short f2bf(float x){
  unsigned int u = __float_as_uint(x);
  u = (u + 0x7fffu + ((u >> 16) & 1u)) >> 16;
  return (unsigned short)u;
}
__device__ inline float bf2f(unsigned short u){
  return __uint_as_float(((unsigned int)u) << 16);
}

__device__ float blockReduceSum(float x, float* red){
  int tid = threadIdx.x;
  red[tid] = x; __syncthreads();
  #pragma unroll
  for (int off = 128; off > 0; off >>= 1){
    if (tid < off) red[tid] += red[tid + off];
    __syncthreads();
  }
  float r = red[0]; __syncthreads();
  return r;
}

// fp32 norm + bf16 conversion; grid.y = src select. Also folds all state init.
__global__ __launch_bounds__(256) void prep_kernel(
    const float* __restrict__ preds, const float* __restrict__ labels,
    unsigned short* __restrict__ pabf, unsigned short* __restrict__ pbbf,
    float* __restrict__ pn, float* __restrict__ ln,
    float* __restrict__ cost, float* __restrict__ currency,
    int* __restrict__ dmin, float* __restrict__ PL,
    float* __restrict__ scal, float* __restrict__ out){
  int s = blockIdx.y;
  if (s == 0){
    int i = blockIdx.x * 256 + threadIdx.x;
    if (i < B_ * N_){ cost[i] = 1.f; currency[i] = 1.f; }
    if (i < 2 * B_ * D_) PL[i] = 0.f;
    if (i < B_ * 4) scal[i] = 0.f;
    if (i < B_) dmin[i] = 0x7f7fffff;  // FLT_MAX bits
    if (i == 0) out[0] = 0.f;
  }
  const float* src = s ? labels : preds;
  unsigned short* dst = s ? pbbf : pabf;
  float* norms = s ? ln : pn;
  int gw = (blockIdx.x * blockDim.x + threadIdx.x) >> 6;
  int lane = threadIdx.x & 63;
  const float4 v = ((const float4*)(src + (size_t)gw * D_))[lane];
  float sum = v.x*v.x + v.y*v.y + v.z*v.z + v.w*v.w;
  #pragma unroll
  for (int off = 32; off >= 1; off >>= 1) sum += __shfl_xor(sum, off);
  if (lane == 0) norms[gw] = sum;
  ushort4 o; o.x = f2bf(v.x); o.y = f2bf(v.y); o.z = f2bf(v.z); o.w = f2bf(v.w);
  ((ushort4*)(dst + (size_t)gw * D_))[lane] = o;
}

// d[b][n][m] = pn[n] + ln[m] - 2*dot via bf16 MFMA; NO stores — only per-batch min.
// 256x256 block tile, 512 threads, wave tile 128x64, BK=64, dbuf LDS 128 KB.
// Proven-conflict-free LDS layout (128-B rows, XOR r&7) + measured-ideal
// batch->XCD pinning. ROUND-10 FIX: epilogue operands (pn/ln) loaded AFTER the
// K-loop — round 9 preloaded them pre-loop, pushing the wave to the 256-reg cap
// and spilling ~15 dwords/thread to scratch (WRITE_SIZE 30 MB).
__global__ __launch_bounds__(512, 2) void gemm_minmax(
    const unsigned short* __restrict__ pa, const unsigned short* __restrict__ pbm,
    const float* __restrict__ pn, const float* __restrict__ ln,
    int* __restrict__ dmin)
{
  int lid = blockIdx.x;              // 1024 blocks, round-robin over 8 XCDs
  int l = lid >> 3;                  // 0..127 sequential per XCD
  int b = 2 * (lid & 7) + (l >> 6);  // 2 batches per XCD
  int t = l & 63;
  int tm = (t & 7) * 256, tn = (t >> 3) * 256;  // tm fastest: B-slice stays L2-hot
  const unsigned short* A  = pa  + (size_t)b * N_ * D_;
  const unsigned short* Bm = pbm + (size_t)b * N_ * D_;
  __shared__ __align__(16) unsigned short As[2][256 * 64];
  __shared__ __align__(16) unsigned short Bs[2][256 * 64];
  __shared__ float minred[8];
  int tid = threadIdx.x, lane = tid & 63, w = tid >> 6;
  int wm = (w >> 2) * 128, wn = (w & 3) * 64;
  int quad = lane >> 4, l15 = lane & 15;

  f4 acc[8][4];
  #pragma unroll
  for (int i = 0; i < 8; i++)
    #pragma unroll
    for (int j = 0; j < 4; j++) acc[i][j] = (f4)0.f;

  int lr = lane >> 3, ch = lane & 7;
  int gch = (ch ^ lr) * 8;           // XOR swizzle on the GLOBAL side (r&7 == lr)

  // prefetch tile 0 into buffer 0 (4 rounds of 64 rows each for As and Bs)
  #pragma unroll
  for (int p = 0; p < 4; p++){
    int R = p * 64 + w * 8;
    int r = R + lr;
    __builtin_amdgcn_global_load_lds(
        (const AS1 unsigned int*)(const void*)&A[(size_t)(tm + r) * D_ + gch],
        (AS3 unsigned int*)(void*)&As[0][R * 64], 16, 0, 0);
    __builtin_amdgcn_global_load_lds(
        (const AS1 unsigned int*)(const void*)&Bm[(size_t)(tn + r) * D_ + gch],
        (AS3 unsigned int*)(void*)&Bs[0][R * 64], 16, 0, 0);
  }

  int buf = 0;
  for (int ki = 0; ki < 4; ki++){
    __syncthreads();   // drains buf's loads (issued one compute-phase ago)
    if (ki < 3){
      int kt = (ki + 1) * 64;
      #pragma unroll
      for (int p = 0; p < 4; p++){
        int R = p * 64 + w * 8;
        int r = R + lr;
        __builtin_amdgcn_global_load_lds(
            (const AS1 unsigned int*)(const void*)&A[(size_t)(tm + r) * D_ + kt + gch],
            (AS3 unsigned int*)(void*)&As[buf ^ 1][R * 64], 16, 0, 0);
        __builtin_amdgcn_global_load_lds(
            (const AS1 unsigned int*)(const void*)&Bm[(size_t)(tn + r) * D_ + kt + gch],
            (AS3 unsigned int*)(void*)&Bs[buf ^ 1][R * 64], 16, 0, 0);
      }
    }
    #pragma unroll
    for (int ks = 0; ks < 2; ks++){
      short8 af[8], bf[4];
      int j = ks * 4 + quad;
      #pragma unroll
      for (int i = 0; i < 8; i++){
        int ra = wm + i * 16 + l15;
        af[i] = *(const short8*)(&As[buf][ra * 64 + ((j ^ (ra & 7)) * 8)]);
      }
      #pragma unroll
      for (int jj = 0; jj < 4; jj++){
        int rb = wn + jj * 16 + l15;
        bf[jj] = *(const short8*)(&Bs[buf][rb * 64 + ((j ^ (rb & 7)) * 8)]);
      }
      #pragma unroll
      for (int i = 0; i < 8; i++)
        #pragma unroll
        for (int jj = 0; jj < 4; jj++)
          acc[i][jj] = __builtin_amdgcn_mfma_f32_16x16x32_bf16(af[i], bf[jj], acc[i][jj], 0, 0, 0);
    }
    buf ^= 1;
  }

  // epilogue: load pn/ln NOW (K-independent; loading pre-loop caused the round-9
  // scratch spill). C/D layout col = lane&15, row = quad*4 + reg.
  float4 pnr[8];
  float lnr[4];
  #pragma unroll
  for (int i = 0; i < 8; i++)
    pnr[i] = *(const float4*)&pn[(size_t)b * N_ + tm + wm + i * 16 + quad * 4];
  #pragma unroll
  for (int jj = 0; jj < 4; jj++)
    lnr[jj] = ln[(size_t)b * N_ + tn + wn + jj * 16 + l15];

  float mind = 3.4e38f;
  #pragma unroll
  for (int i = 0; i < 8; i++){
    float pv[4] = {pnr[i].x, pnr[i].y, pnr[i].z, pnr[i].w};
    #pragma unroll
    for (int jj = 0; jj < 4; jj++){
      #pragma unroll
      for (int reg = 0; reg < 4; reg++){
        float v = pv[reg] + lnr[jj] - 2.f * acc[i][jj][reg];
        mind = fminf(mind, v);
      }
    }
  }
  #pragma unroll
  for (int off = 32; off >= 1; off >>= 1) mind = fminf(mind, __shfl_xor(mind, off));
  if (lane == 0) minred[w] = mind;
  __syncthreads();
  if (tid == 0){
    float m = minred[0];
    #pragma unroll
    for (int q = 1; q < 8; q++) m = fminf(m, minred[q]);
    atomicMin(&dmin[b], __float_as_int(fmaxf(m, 0.f)));
  }
}

// Exact fallback for the 6 negative exp-factors (skipped when provably
// negligible: B*N^2*dmax*e^{ef*dmin}/EPS < 1e-3 iff ef*(dmin-8) < -55),
// followed by the ef=0 closed-form scalars.
__global__ __launch_bounds__(256) void fb_all(
    const unsigned short* __restrict__ pabf, const unsigned short* __restrict__ pbbf,
    const float* __restrict__ pn, const float* __restrict__ ln,
    float* __restrict__ cost, float* __restrict__ currency,
    const int* __restrict__ dmin, float* __restrict__ out,
    float* __restrict__ alpha, float* __restrict__ v, float* __restrict__ scal)
{
  const float EF[6] = {-256.f, -64.f, -16.f, -4.f, -1.f, -0.25f};
  int b = blockIdx.x, tid = threadIdx.x;
  float dm = __int_as_float(dmin[b]);
  __shared__ float red[256];
  __shared__ float alpha_l[N_];
  __shared__ float prow[D_];
  const unsigned short* A  = pabf + (size_t)b * N_ * D_;
  const unsigned short* Bm = pbbf + (size_t)b * N_ * D_;
  const float* pnb = pn + (size_t)b * N_;
  const float* lnb = ln + (size_t)b * N_;
  float* costb = cost + (size_t)b * N_;
  float* curb  = currency + (size_t)b * N_;
  for (int it = 0; it < 6; it++){
    float ef = EF[it];
    if (ef * (dm - 8.f) < -55.f) continue;   // provably negligible contribution
    // ---- exact slow path (not expected to execute for this input) ----
    float cost_c[8], colsum_c[8], bw_c[8], costnew_c[8];
    #pragma unroll
    for (int j = 0; j < 8; j++){ cost_c[j] = costb[j*256+tid]; colsum_c[j] = 0.f; }
    for (int r = 0; r < N_; r++){
      prow[tid] = bf2f(A[(size_t)r * D_ + tid]);
      __syncthreads();
      float s_c[8], rs = 0.f;
      for (int j = 0; j < 8; j++){
        int m = j*256+tid; float dot = 0.f;
        for (int k = 0; k < D_; k++) dot += prow[k] * bf2f(Bm[(size_t)m * D_ + k]);
        float d = pnb[r] + lnb[m] - 2.f*dot;
        float s = __expf(ef * d) * cost_c[j];
        s_c[j] = s; rs += s;
      }
      float tot = blockReduceSum(rs, red);
      float a = curb[r] / (tot + EPS_);
      if (tid == 0) alpha_l[r] = a;
      #pragma unroll
      for (int j = 0; j < 8; j++) colsum_c[j] += s_c[j] * a;
      __syncthreads();
    }
    #pragma unroll
    for (int j = 0; j < 8; j++){
      float cs = colsum_c[j];
      float bw = fminf(cost_c[j] / (cs + EPS_), 1.f);
      bw_c[j] = bw; costnew_c[j] = fmaxf(cost_c[j] - bw*cs, 0.f);
    }
    float contrib = 0.f;
    for (int r = 0; r < N_; r++){
      prow[tid] = bf2f(A[(size_t)r * D_ + tid]);
      __syncthreads();
      float a = alpha_l[r], rbs = 0.f;
      for (int j = 0; j < 8; j++){
        int m = j*256+tid; float dot = 0.f;
        for (int k = 0; k < D_; k++) dot += prow[k] * bf2f(Bm[(size_t)m * D_ + k]);
        float d = pnb[r] + lnb[m] - 2.f*dot;
        float bid = __expf(ef * d) * cost_c[j] * a * bw_c[j];
        rbs += bid; contrib += bid * d;
      }
      float tot = blockReduceSum(rbs, red);
      if (tid == 0) curb[r] = fmaxf(curb[r] - tot, 0.f);
      __syncthreads();
    }
    #pragma unroll
    for (int j = 0; j < 8; j++) costb[j*256+tid] = costnew_c[j];
    float ctot = blockReduceSum(contrib, red);
    if (tid == 0) atomicAdd(out, ctot);
    __syncthreads();
  }
  // ---- fused ef=0 closed-form scalars: exp(0*d)=1 exactly, so
  // sum(bids*d) = Spn*Sv + Sa*Sln - 2*(sum alpha*p).(sum v*l). ----
  float* ab = alpha + (size_t)b * N_;
  float* vb = v + (size_t)b * N_;
  float s = 0.f;
  #pragma unroll
  for (int j = 0; j < 8; j++) s += costb[j*256+tid];
  float Sc = blockReduceSum(s, red);
  float sa = 0.f, spn = 0.f;
  #pragma unroll
  for (int j = 0; j < 8; j++){
    int i = j*256+tid;
    float a = curb[i] / (Sc + EPS_);
    ab[i] = a; sa += a; spn += a * pnb[i];
  }
  float Sa  = blockReduceSum(sa, red);
  float Spn = blockReduceSum(spn, red);
  float sv = 0.f, sln = 0.f;
  #pragma unroll
  for (int j = 0; j < 8; j++){
    int i = j*256+tid;
    float c = costb[j*256+tid];
    float bw = fminf(c / (c * Sa + EPS_), 1.f);
    float vv = c * bw;
    vb[i] = vv; sv += vv; sln += vv * lnb[i];
  }
  float Sv  = blockReduceSum(sv, red);
  float Sln = blockReduceSum(sln, red);
  if (tid == 0){
    scal[b*4+0] = Sa; scal[b*4+1] = Sv; scal[b*4+2] = Spn; scal[b*4+3] = Sln;
  }
}

// P_b = sum_r alpha_r * preds[b][r][:], L_b = sum_m v_m * labels[b][m][:]
__global__ __launch_bounds__(256) void cf_wsum(
    const unsigned short* __restrict__ pabf, const unsigned short* __restrict__ pbbf,
    const float* __restrict__ alpha, const float* __restrict__ v,
    float* __restrict__ PL)
{
  int chunk = blockIdx.x, src = blockIdx.y, b = blockIdx.z, tid = threadIdx.x;
  int g = tid >> 6, c4 = (tid & 63) * 4;
  const unsigned short* X = (src ? pbbf : pabf) + ((size_t)b * N_ + chunk * 64) * D_;
  const float* wv = (src ? v : alpha) + (size_t)b * N_ + chunk * 64;
  __shared__ float wl[64];
  __shared__ float part[4][D_];
  if (tid < 64) wl[tid] = wv[tid];
  __syncthreads();
  f4 acc = (f4)0.f;
  for (int r = g * 16; r < g * 16 + 16; r++){
    uint2 pk = *(const uint2*)&X[(size_t)r * D_ + c4];
    float wr = wl[r];
    acc[0] = fmaf(wr, __uint_as_float(pk.x << 16), acc[0]);
    acc[1] = fmaf(wr, __uint_as_float(pk.x & 0xffff0000u), acc[1]);
    acc[2] = fmaf(wr, __uint_as_float(pk.y << 16), acc[2]);
    acc[3] = fmaf(wr, __uint_as_float(pk.y & 0xffff0000u), acc[3]);
  }
  #pragma unroll
  for (int q = 0; q < 4; q++) part[g][c4 + q] = acc[q];
  __syncthreads();
  float s = part[0][tid] + part[1][tid] + part[2][tid] + part[3][tid];
  atomicAdd(&PL[((size_t)src * B_ + b) * D_ + tid], s);
}

__global__ __launch_bounds__(256) void cf_final(
    const float* __restrict__ PL, const float* __restrict__ scal,
    float* __restrict__ out)
{
  int b = blockIdx.x, tid = threadIdx.x;
  __shared__ float red[256];
  float p = PL[(size_t)b * D_ + tid] * PL[((size_t)B_ + b) * D_ + tid];
  float dot = blockReduceSum(p, red);
  if (tid == 0){
    float Sa = scal[b*4+0], Sv = scal[b*4+1], Spn = scal[b*4+2], Sln = scal[b*4+3];
    atomicAdd(out, Spn * Sv + Sa * Sln - 2.f * dot);
  }
}

extern "C" void kernel_launch(void* const* d_in, const int* in_sizes, int n_in,
                              void* d_out, int out_size, void* d_ws, size_t ws_size,
                              hipStream_t stream)
{
  const float* preds  = (const float*)d_in[0];
  const float* labels = (const float*)d_in[1];
  float* out = (float*)d_out;
  char* ws = (char*)d_ws;
  const size_t BN = (size_t)B_ * N_;
  size_t off = 0;
  float* cost     = (float*)(ws + off); off += BN * 4;
  float* currency = (float*)(ws + off); off += BN * 4;
  float* alpha    = (float*)(ws + off); off += BN * 4;
  float* v        = (float*)(ws + off); off += BN * 4;
  float* pn       = (float*)(ws + off); off += BN * 4;
  float* ln       = (float*)(ws + off); off += BN * 4;
  int*   dmin     = (int*)(ws + off);   off += 256;
  float* scal     = (float*)(ws + off); off += 256;
  float* PL       = (float*)(ws + off); off += (size_t)2 * B_ * D_ * 4;
  unsigned short* pabf = (unsigned short*)(ws + off); off += BN * D_ * 2;
  unsigned short* pbbf = (unsigned short*)(ws + off); off += BN * D_ * 2;

  prep_kernel<<<dim3((unsigned)(BN / 4), 2), 256, 0, stream>>>(
      preds, labels, pabf, pbbf, pn, ln, cost, currency, dmin, PL, scal, out);
  gemm_minmax<<<dim3(1024), 512, 0, stream>>>(pabf, pbbf, pn, ln, dmin);
  fb_all<<<dim3(B_), 256, 0, stream>>>(pabf, pbbf, pn, ln, cost, currency, dmin, out,
                                       alpha, v, scal);
  cf_wsum<<<dim3(32, 2, B_), 256, 0, stream>>>(pabf, pbbf, alpha, v, PL);
  cf_final<<<dim3(B_), 256, 0, stream>>>(PL, scal, out);
}